// Round 1
// baseline (442.556 us; speedup 1.0000x reference)
//
#include <hip/hip_runtime.h>

namespace {

constexpr int    TT     = 2048;
constexpr int    BB     = 128;
constexpr int    CHUNK  = 8;                  // timesteps per chunk (shfl scan width)
constexpr int    NCHUNK = TT / CHUNK;         // 256 chunks per batch
constexpr float  DT     = 0.02f;
constexpr size_t HALF   = (size_t)TT * BB * 16;   // floats per (real|imag) half of d_out
constexpr int    NBLK   = (BB * TT) / 256;    // 1024 blocks = exactly 4 blocks/CU * 256 CUs

// C = A @ B, complex 4x4, row-major flat [16]
__device__ __forceinline__ void cmm(const float* __restrict__ ar, const float* __restrict__ ai,
                                    const float* __restrict__ br, const float* __restrict__ bi,
                                    float* __restrict__ cr, float* __restrict__ ci) {
#pragma unroll
    for (int i = 0; i < 4; ++i) {
#pragma unroll
        for (int j = 0; j < 4; ++j) {
            float sr = 0.f, si = 0.f;
#pragma unroll
            for (int k = 0; k < 4; ++k) {
                const float xr = ar[i * 4 + k], xi = ai[i * 4 + k];
                const float yr = br[k * 4 + j], yi = bi[k * 4 + j];
                sr = fmaf(xr, yr, sr);
                sr = fmaf(-xi, yi, sr);
                si = fmaf(xr, yi, si);
                si = fmaf(xi, yr, si);
            }
            cr[i * 4 + j] = sr;
            ci[i * 4 + j] = si;
        }
    }
}

// C += A @ B  (accumulating variant: lets us fold I + A into the expm result
// so A is dead before the second multiply -> peak live set ~96 floats)
__device__ __forceinline__ void cmm_acc(const float* __restrict__ ar, const float* __restrict__ ai,
                                        const float* __restrict__ br, const float* __restrict__ bi,
                                        float* __restrict__ cr, float* __restrict__ ci) {
#pragma unroll
    for (int i = 0; i < 4; ++i) {
#pragma unroll
        for (int j = 0; j < 4; ++j) {
            float sr = cr[i * 4 + j], si = ci[i * 4 + j];
#pragma unroll
            for (int k = 0; k < 4; ++k) {
                const float xr = ar[i * 4 + k], xi = ai[i * 4 + k];
                const float yr = br[k * 4 + j], yi = bi[k * 4 + j];
                sr = fmaf(xr, yr, sr);
                sr = fmaf(-xi, yi, sr);
                si = fmaf(xr, yi, si);
                si = fmaf(xi, yr, si);
            }
            cr[i * 4 + j] = sr;
            ci[i * 4 + j] = si;
        }
    }
}

// bf16 truncation pack: two f32 -> one uint (lo = a, hi = b)
__device__ __forceinline__ unsigned int pack2(float a, float b) {
    return (__float_as_uint(a) >> 16) | (__float_as_uint(b) & 0xFFFF0000u);
}
__device__ __forceinline__ float unlo(unsigned int u) { return __uint_as_float(u << 16); }
__device__ __forceinline__ float unhi(unsigned int u) { return __uint_as_float(u & 0xFFFF0000u); }

// Grid-wide barrier. Single-use counter per barrier (init kernel zeroes them each
// replay), so no generation flag / reset race. Correctness chain:
//   producer stores -> __syncthreads (compiler emits s_waitcnt vmcnt(0) before
//   s_barrier, so all block stores are in L2) -> leader __threadfence (agent
//   release: buffer_wbl2, stores visible device-wide) -> device-scope atomicAdd.
//   Consumers spin on agent-scope ACQUIRE loads (buffer_inv invalidates this
//   CU's L1 + XCD L2) -> __syncthreads -> block reads fresh data.
// Deadlock-free because grid == 1024 == 4 blocks/CU * 256 CUs, co-residency
// guaranteed by __launch_bounds__(256,4) (VGPR<=128) + 34.8 KB LDS (<=4/CU).
__device__ __forceinline__ void gsync(unsigned int* cnt) {
    __syncthreads();
    if (threadIdx.x == 0) {
        __threadfence();
        __hip_atomic_fetch_add(cnt, 1u, __ATOMIC_ACQ_REL, __HIP_MEMORY_SCOPE_AGENT);
        while (__hip_atomic_load(cnt, __ATOMIC_ACQUIRE, __HIP_MEMORY_SCOPE_AGENT) <
               (unsigned int)NBLK) {
            __builtin_amdgcn_s_sleep(1);
        }
    }
    __syncthreads();
}

} // namespace

__global__ void k_init(unsigned int* bar) {
    bar[0] = 0u;
    bar[1] = 0u;
}

// ---------------------------------------------------------------------------
// Fused kernel. Tile = 16 t x 16 b (same as old kD). Thread (bloc=tid>>4 over b,
// tloc=tid&15 over t); within a wave lane = (bloc&3)*16 + tloc, so each 8-lane
// group holds 8 consecutive timesteps of one b -> shfl chunk scan works.
//   phase 1: A = -i*dt*H, expm (deg-4 PS), 8-lane Kogge-Stone prefix.
//            L stays in 16 packed-bf16 REGISTERS (never touches HBM).
//            Chunk totals (f32) -> global.           === gsync ===
//   phase 2: blocks 0..127: per-batch 8-round KS carry scan in LDS. === gsync ===
//   phase 3: o = L @ carry, LDS transpose [b][t]->[t][b], coalesced write.
// ---------------------------------------------------------------------------
__global__ __launch_bounds__(256, 4) void k_fused(
        const float* __restrict__ hr, const float* __restrict__ hi,
        const float* __restrict__ sr, const float* __restrict__ si,
        float* __restrict__ out, float* __restrict__ totals,
        float* __restrict__ carry, unsigned int* __restrict__ bar) {
    // union'd scratch: phase 2 uses [0 .. 2*16*256) as sRe/sIm (32 KB),
    // phase 3 uses all 32*272 floats (34.8 KB) as the transpose buffer.
    __shared__ float scratch[32 * 272];

    const int tid   = threadIdx.x;
    const int bid   = blockIdx.x;
    const int tileT = bid & 127;
    const int tileB = bid >> 7;
    const int t0 = tileT * 16, b0 = tileB * 16;
    const int bloc = tid >> 4, tloc = tid & 15;
    const int lane = tid & 63;
    const int sub  = tloc & 7;                 // position within 8-step chunk
    const int b = b0 + bloc;
    const int t = t0 + tloc;

    // ---------------- phase 1: expm + chunk prefix (registers only) ----------
    float er[16], ei[16];
    {
        float a_r[16], a_i[16];
        const size_t gi = (size_t)b * TT + t;
        const float4* p4r = reinterpret_cast<const float4*>(hr) + gi * 4;
        const float4* p4i = reinterpret_cast<const float4*>(hi) + gi * 4;
#pragma unroll
        for (int v = 0; v < 4; ++v) {
            const float4 rr = p4r[v];
            const float4 im = p4i[v];
            a_r[v * 4 + 0] = DT * im.x;  a_i[v * 4 + 0] = -DT * rr.x;
            a_r[v * 4 + 1] = DT * im.y;  a_i[v * 4 + 1] = -DT * rr.y;
            a_r[v * 4 + 2] = DT * im.z;  a_i[v * 4 + 2] = -DT * rr.z;
            a_r[v * 4 + 3] = DT * im.w;  a_i[v * 4 + 3] = -DT * rr.w;
        }

        // E = (I + A) + A2 @ (I/2 + A/6 + A2/24)
        float a2r[16], a2i[16];
        cmm(a_r, a_i, a_r, a_i, a2r, a2i);
        float t6r[16], t6i[16];
#pragma unroll
        for (int e = 0; e < 16; ++e) {
            const float d = (e % 5 == 0) ? 1.0f : 0.0f;
            t6r[e] = fmaf(a_r[e], 1.f / 6.f, d * 0.5f);
            t6r[e] = fmaf(a2r[e], 1.f / 24.f, t6r[e]);
            t6i[e] = a_i[e] * (1.f / 6.f);
            t6i[e] = fmaf(a2i[e], 1.f / 24.f, t6i[e]);
            er[e]  = a_r[e] + d;               // E starts as I + A  (A dead after)
            ei[e]  = a_i[e];
        }
        cmm_acc(a2r, a2i, t6r, t6i, er, ei);
    }

    // 8-lane Kogge-Stone inclusive prefix (3 rounds); groups of 8 lanes are
    // aligned in lane space (lane = (bloc&3)*16 + tloc, sub = lane & 7).
#pragma unroll
    for (int d = 1; d < CHUNK; d <<= 1) {
        int src = lane - d;
        if (src < 0) src = 0;                  // clamped junk, discarded by select
        float qr[16], qi[16];
#pragma unroll
        for (int e = 0; e < 16; ++e) {
            qr[e] = __shfl(er[e], src, 64);
            qi[e] = __shfl(ei[e], src, 64);
        }
        float nr[16], ni[16];
        cmm(er, ei, qr, qi, nr, ni);
        const bool pred = (sub >= d);
#pragma unroll
        for (int e = 0; e < 16; ++e) {
            er[e] = pred ? nr[e] : er[e];
            ei[e] = pred ? ni[e] : ei[e];
        }
    }

    // chunk totals (f32, vectorized)
    if (sub == CHUNK - 1) {
        float4* tp = reinterpret_cast<float4*>(totals + ((size_t)b * NCHUNK + (t >> 3)) * 32);
        tp[0] = make_float4(er[0],  er[1],  er[2],  er[3]);
        tp[1] = make_float4(er[4],  er[5],  er[6],  er[7]);
        tp[2] = make_float4(er[8],  er[9],  er[10], er[11]);
        tp[3] = make_float4(er[12], er[13], er[14], er[15]);
        tp[4] = make_float4(ei[0],  ei[1],  ei[2],  ei[3]);
        tp[5] = make_float4(ei[4],  ei[5],  ei[6],  ei[7]);
        tp[6] = make_float4(ei[8],  ei[9],  ei[10], ei[11]);
        tp[7] = make_float4(ei[12], ei[13], ei[14], ei[15]);
    }

    // L packed bf16 into 16 VGPRs — held live across both barriers.
    unsigned int Lp[16];
#pragma unroll
    for (int k = 0; k < 8; ++k) {
        Lp[k]     = pack2(er[2 * k], er[2 * k + 1]);
        Lp[8 + k] = pack2(ei[2 * k], ei[2 * k + 1]);
    }

    gsync(bar + 0);

    // ---------------- phase 2: per-batch carry scan (blocks 0..127) ----------
    if (bid < BB) {
        float* sRe = scratch;                  // [16][NCHUNK]
        float* sIm = scratch + 16 * NCHUNK;
        const int ct = tid;                    // 0..255 = chunk index

        float pr[16], pi[16];
        if (ct == 0) {
            const float4* s4r = reinterpret_cast<const float4*>(sr) + bid * 4;
            const float4* s4i = reinterpret_cast<const float4*>(si) + bid * 4;
#pragma unroll
            for (int q = 0; q < 4; ++q) {
                const float4 xr = s4r[q], xi = s4i[q];
                pr[q * 4 + 0] = xr.x; pr[q * 4 + 1] = xr.y; pr[q * 4 + 2] = xr.z; pr[q * 4 + 3] = xr.w;
                pi[q * 4 + 0] = xi.x; pi[q * 4 + 1] = xi.y; pi[q * 4 + 2] = xi.z; pi[q * 4 + 3] = xi.w;
            }
        } else {
            const float4* tp = reinterpret_cast<const float4*>(
                totals + ((size_t)bid * NCHUNK + ct - 1) * 32);
#pragma unroll
            for (int q = 0; q < 4; ++q) {
                const float4 xr = tp[q], xi = tp[4 + q];
                pr[q * 4 + 0] = xr.x; pr[q * 4 + 1] = xr.y; pr[q * 4 + 2] = xr.z; pr[q * 4 + 3] = xr.w;
                pi[q * 4 + 0] = xi.x; pi[q * 4 + 1] = xi.y; pi[q * 4 + 2] = xi.z; pi[q * 4 + 3] = xi.w;
            }
        }

#pragma unroll
        for (int e = 0; e < 16; ++e) {
            sRe[e * NCHUNK + ct] = pr[e];
            sIm[e * NCHUNK + ct] = pi[e];
        }
        __syncthreads();

        for (int d = 1; d < NCHUNK; d <<= 1) {
            if (ct >= d) {
                float qr[16], qi[16];
#pragma unroll
                for (int e = 0; e < 16; ++e) {
                    qr[e] = sRe[e * NCHUNK + ct - d];
                    qi[e] = sIm[e * NCHUNK + ct - d];
                }
                float nr[16], ni[16];
                cmm(pr, pi, qr, qi, nr, ni);
#pragma unroll
                for (int e = 0; e < 16; ++e) { pr[e] = nr[e]; pi[e] = ni[e]; }
            }
            __syncthreads();
            if (ct >= d) {
#pragma unroll
                for (int e = 0; e < 16; ++e) {
                    sRe[e * NCHUNK + ct] = pr[e];
                    sIm[e * NCHUNK + ct] = pi[e];
                }
            }
            __syncthreads();
        }

        float4* cp = reinterpret_cast<float4*>(carry + ((size_t)bid * NCHUNK + ct) * 32);
        cp[0] = make_float4(pr[0],  pr[1],  pr[2],  pr[3]);
        cp[1] = make_float4(pr[4],  pr[5],  pr[6],  pr[7]);
        cp[2] = make_float4(pr[8],  pr[9],  pr[10], pr[11]);
        cp[3] = make_float4(pr[12], pr[13], pr[14], pr[15]);
        cp[4] = make_float4(pi[0],  pi[1],  pi[2],  pi[3]);
        cp[5] = make_float4(pi[4],  pi[5],  pi[6],  pi[7]);
        cp[6] = make_float4(pi[8],  pi[9],  pi[10], pi[11]);
        cp[7] = make_float4(pi[12], pi[13], pi[14], pi[15]);
    }

    gsync(bar + 1);

    // ---------------- phase 3: o = L @ carry, LDS transpose, coalesced write --
    {
        float l_r[16], l_i[16];
#pragma unroll
        for (int k = 0; k < 8; ++k) {
            l_r[2 * k] = unlo(Lp[k]);     l_r[2 * k + 1] = unhi(Lp[k]);
            l_i[2 * k] = unlo(Lp[8 + k]); l_i[2 * k + 1] = unhi(Lp[8 + k]);
        }

        float c_r[16], c_i[16];
        const float4* cp = reinterpret_cast<const float4*>(
            carry + ((size_t)b * NCHUNK + (t >> 3)) * 32);
#pragma unroll
        for (int q = 0; q < 4; ++q) {
            const float4 xr = cp[q], xi = cp[4 + q];
            c_r[q * 4 + 0] = xr.x; c_r[q * 4 + 1] = xr.y; c_r[q * 4 + 2] = xr.z; c_r[q * 4 + 3] = xr.w;
            c_i[q * 4 + 0] = xi.x; c_i[q * 4 + 1] = xi.y; c_i[q * 4 + 2] = xi.z; c_i[q * 4 + 3] = xi.w;
        }

        float o_r[16], o_i[16];
        cmm(l_r, l_i, c_r, c_i, o_r, o_i);

        const int slot = bloc * 17 + tloc;     // row pad 17 -> <=2-way aliasing (free)
#pragma unroll
        for (int e = 0; e < 16; ++e) {
            scratch[e * 272 + slot]        = o_r[e];
            scratch[(e + 16) * 272 + slot] = o_i[e];
        }
    }
    __syncthreads();
    {
        const int u = tid >> 4;                // t offset in tile
        const int v = tid & 15;                // b offset in tile
        const int slot = v * 17 + u;

        float r2[16], i2[16];
#pragma unroll
        for (int e = 0; e < 16; ++e) {
            r2[e] = scratch[e * 272 + slot];
            i2[e] = scratch[(e + 16) * 272 + slot];
        }

        const size_t oi = ((size_t)(t0 + u) * BB + (b0 + v)) * 16;
        float4* orp = reinterpret_cast<float4*>(out + oi);
        float4* oip = reinterpret_cast<float4*>(out + HALF + oi);
#pragma unroll
        for (int w = 0; w < 4; ++w) {
            orp[w] = make_float4(r2[w * 4 + 0], r2[w * 4 + 1], r2[w * 4 + 2], r2[w * 4 + 3]);
            oip[w] = make_float4(i2[w * 4 + 0], i2[w * 4 + 1], i2[w * 4 + 2], i2[w * 4 + 3]);
        }
    }
}

extern "C" void kernel_launch(void* const* d_in, const int* in_sizes, int n_in,
                              void* d_out, int out_size, void* d_ws, size_t ws_size,
                              hipStream_t stream) {
    const float* hr = (const float*)d_in[0];
    const float* hi = (const float*)d_in[1];
    const float* sr = (const float*)d_in[2];
    const float* si = (const float*)d_in[3];
    float* out    = (float*)d_out;
    float* totals = (float*)d_ws;                                   // 4 MiB
    float* carry  = (float*)d_ws + (size_t)BB * NCHUNK * 32;        // 4 MiB
    unsigned int* bar = (unsigned int*)((float*)d_ws + 2 * (size_t)BB * NCHUNK * 32);

    k_init <<<1, 1, 0, stream>>>(bar);
    k_fused<<<NBLK, 256, 0, stream>>>(hr, hi, sr, si, out, totals, carry, bar);
}

// Round 2
// 159.164 us; speedup vs baseline: 2.7805x; 2.7805x over previous
//
#include <hip/hip_runtime.h>

namespace {

constexpr int    TT    = 2048;
constexpr int    BB    = 128;
constexpr int    CHUNK = 8;                 // timesteps per shfl-scan chunk
constexpr int    TPB   = 512;               // threads per block (one timestep each)
constexpr int    BPB   = TT / TPB;          // 4 blocks per batch = chain depth
constexpr int    NBLK  = BB * BPB;          // 512 blocks = 2/CU * 256 CU (co-resident)
constexpr int    NCH   = TPB / CHUNK;       // 64 chunks per block
constexpr float  DT    = 0.02f;
constexpr size_t HALF  = (size_t)TT * BB * 16;

// C = A @ B, complex 4x4, row-major flat [16]
__device__ __forceinline__ void cmm(const float* __restrict__ ar, const float* __restrict__ ai,
                                    const float* __restrict__ br, const float* __restrict__ bi,
                                    float* __restrict__ cr, float* __restrict__ ci) {
#pragma unroll
    for (int i = 0; i < 4; ++i) {
#pragma unroll
        for (int j = 0; j < 4; ++j) {
            float sr = 0.f, si = 0.f;
#pragma unroll
            for (int k = 0; k < 4; ++k) {
                const float xr = ar[i * 4 + k], xi = ai[i * 4 + k];
                const float yr = br[k * 4 + j], yi = bi[k * 4 + j];
                sr = fmaf(xr, yr, sr);
                sr = fmaf(-xi, yi, sr);
                si = fmaf(xr, yi, si);
                si = fmaf(xi, yr, si);
            }
            cr[i * 4 + j] = sr;
            ci[i * 4 + j] = si;
        }
    }
}

// C += A @ B
__device__ __forceinline__ void cmm_acc(const float* __restrict__ ar, const float* __restrict__ ai,
                                        const float* __restrict__ br, const float* __restrict__ bi,
                                        float* __restrict__ cr, float* __restrict__ ci) {
#pragma unroll
    for (int i = 0; i < 4; ++i) {
#pragma unroll
        for (int j = 0; j < 4; ++j) {
            float sr = cr[i * 4 + j], si = ci[i * 4 + j];
#pragma unroll
            for (int k = 0; k < 4; ++k) {
                const float xr = ar[i * 4 + k], xi = ai[i * 4 + k];
                const float yr = br[k * 4 + j], yi = bi[k * 4 + j];
                sr = fmaf(xr, yr, sr);
                sr = fmaf(-xi, yi, sr);
                si = fmaf(xr, yi, si);
                si = fmaf(xi, yr, si);
            }
            cr[i * 4 + j] = sr;
            ci[i * 4 + j] = si;
        }
    }
}

} // namespace

__global__ void k_init(unsigned int* flag) { flag[threadIdx.x] = 0u; }

// ---------------------------------------------------------------------------
// Single-pass chained scan. Block = 512 consecutive timesteps of one batch.
//   phase 1: A = -i*dt*H, expm (deg-4 PS), 8-lane Kogge-Stone chunk prefix.
//            L stays in f32 REGISTERS. Chunk totals -> LDS.
//   wave 0 : 6-round shfl scan over 64 chunk totals -> IP_c (stored to LDS).
//   chain  : block j spins on flag[bid-1] (ONE spinner per line — no
//            contention), reads predecessor inclusive prefix P (relaxed-agent
//            payload, acquire flag: round-1-verified atomic recipe),
//            carr[c+1] = IP_c @ P, lane group publishes carr[64] + release flag.
//   phase 3: out[t][b] = L @ carr[chunk]. Per-lane 64-B full-sector writes.
// Deadlock-free: VGPR<=128 (launch_bounds) + 16.5 KB LDS -> capacity
// 2 blocks/CU * 256 CU = 1024 >= grid 512; all blocks co-resident.
// ---------------------------------------------------------------------------
__global__ __launch_bounds__(TPB, 4) void k_main(
        const float* __restrict__ hr, const float* __restrict__ hi,
        const float* __restrict__ sr, const float* __restrict__ si,
        float* __restrict__ out, float* __restrict__ prefix,
        unsigned int* __restrict__ flag) {
    __shared__ float tot[32 * NCH];          // [e 0..31][c 0..63]  (later: IP)
    __shared__ float carr[32 * (NCH + 1)];   // [e][col]; col0 = P_prev, col c+1 = IP_c @ P

    const int tid    = threadIdx.x;
    const int bid    = blockIdx.x;
    const int blockT = bid & (BPB - 1);
    const int b      = bid >> 2;             // BPB == 4
    const int t      = blockT * TPB + tid;
    const int lane   = tid & 63;
    const int sub    = tid & (CHUNK - 1);
    const int c      = tid >> 3;             // chunk within block, 0..63

    // ---------------- phase 1: expm + chunk prefix (registers only) ----------
    float er[16], ei[16];
    {
        float a_r[16], a_i[16];
        const size_t gi = (size_t)b * TT + t;
        const float4* p4r = reinterpret_cast<const float4*>(hr) + gi * 4;
        const float4* p4i = reinterpret_cast<const float4*>(hi) + gi * 4;
#pragma unroll
        for (int v = 0; v < 4; ++v) {
            const float4 rr = p4r[v];
            const float4 im = p4i[v];
            a_r[v * 4 + 0] = DT * im.x;  a_i[v * 4 + 0] = -DT * rr.x;
            a_r[v * 4 + 1] = DT * im.y;  a_i[v * 4 + 1] = -DT * rr.y;
            a_r[v * 4 + 2] = DT * im.z;  a_i[v * 4 + 2] = -DT * rr.z;
            a_r[v * 4 + 3] = DT * im.w;  a_i[v * 4 + 3] = -DT * rr.w;
        }

        // E = (I + A) + A2 @ (I/2 + A/6 + A2/24)
        float a2r[16], a2i[16];
        cmm(a_r, a_i, a_r, a_i, a2r, a2i);
        float t6r[16], t6i[16];
#pragma unroll
        for (int e = 0; e < 16; ++e) {
            const float d = (e % 5 == 0) ? 1.0f : 0.0f;
            t6r[e] = fmaf(a_r[e], 1.f / 6.f, d * 0.5f);
            t6r[e] = fmaf(a2r[e], 1.f / 24.f, t6r[e]);
            t6i[e] = a_i[e] * (1.f / 6.f);
            t6i[e] = fmaf(a2i[e], 1.f / 24.f, t6i[e]);
            er[e]  = a_r[e] + d;
            ei[e]  = a_i[e];
        }
        cmm_acc(a2r, a2i, t6r, t6i, er, ei);
    }

    // 8-lane Kogge-Stone inclusive prefix (3 rounds)
#pragma unroll
    for (int d = 1; d < CHUNK; d <<= 1) {
        int src = lane - d;
        if (src < 0) src = 0;                // clamped junk, discarded by select
        float qr[16], qi[16];
#pragma unroll
        for (int e = 0; e < 16; ++e) {
            qr[e] = __shfl(er[e], src, 64);
            qi[e] = __shfl(ei[e], src, 64);
        }
        float nr[16], ni[16];
        cmm(er, ei, qr, qi, nr, ni);
        const bool pred = (sub >= d);
#pragma unroll
        for (int e = 0; e < 16; ++e) {
            er[e] = pred ? nr[e] : er[e];
            ei[e] = pred ? ni[e] : ei[e];
        }
    }

    // chunk totals -> LDS
    if (sub == CHUNK - 1) {
#pragma unroll
        for (int e = 0; e < 16; ++e) {
            tot[e * NCH + c]        = er[e];
            tot[(16 + e) * NCH + c] = ei[e];
        }
    }
    __syncthreads();

    // ---------------- wave 0: scan 64 chunk totals (shfl KS, 6 rounds) -------
    if (tid < 64) {
        float ipr[16], ipi[16];
#pragma unroll
        for (int e = 0; e < 16; ++e) {
            ipr[e] = tot[e * NCH + tid];
            ipi[e] = tot[(16 + e) * NCH + tid];
        }
#pragma unroll
        for (int d = 1; d < NCH; d <<= 1) {
            int src = tid - d;
            if (src < 0) src = 0;
            float qr[16], qi[16];
#pragma unroll
            for (int e = 0; e < 16; ++e) {
                qr[e] = __shfl(ipr[e], src, 64);
                qi[e] = __shfl(ipi[e], src, 64);
            }
            float nr[16], ni[16];
            cmm(ipr, ipi, qr, qi, nr, ni);
            const bool pred = (tid >= d);
#pragma unroll
            for (int e = 0; e < 16; ++e) {
                ipr[e] = pred ? nr[e] : ipr[e];
                ipi[e] = pred ? ni[e] : ipi[e];
            }
        }
        // store IP over tot (frees registers; only wave 0 reads tot from here)
#pragma unroll
        for (int e = 0; e < 16; ++e) {
            tot[e * NCH + tid]        = ipr[e];
            tot[(16 + e) * NCH + tid] = ipi[e];
        }
    }

    // ---------------- chain: wait for predecessor's inclusive prefix ---------
    if (tid == 0 && blockT != 0) {
        while (__hip_atomic_load(flag + (bid - 1), __ATOMIC_ACQUIRE,
                                 __HIP_MEMORY_SCOPE_AGENT) == 0u) {
            __builtin_amdgcn_s_sleep(1);
        }
    }
    __syncthreads();   // orders spin before payload loads; IP now visible too

    if (tid < 32) {
        float pv;
        if (blockT == 0) {
            pv = (tid < 16) ? sr[b * 16 + tid] : si[b * 16 + (tid - 16)];
        } else {
            pv = __uint_as_float(__hip_atomic_load(
                reinterpret_cast<const unsigned int*>(prefix) + (size_t)(bid - 1) * 32 + tid,
                __ATOMIC_RELAXED, __HIP_MEMORY_SCOPE_AGENT));
        }
        carr[tid * (NCH + 1)] = pv;          // col 0 = P_prev (= carry of chunk 0)
    }
    __syncthreads();

    // ---------------- wave 0: carr[c+1] = IP_c @ P ; publish + release -------
    if (tid < 64) {
        float Ppr[16], Ppi[16];
#pragma unroll
        for (int e = 0; e < 16; ++e) {
            Ppr[e] = carr[e * (NCH + 1)];
            Ppi[e] = carr[(16 + e) * (NCH + 1)];
        }
        float cxr[16], cxi[16];
#pragma unroll
        for (int i = 0; i < 4; ++i) {
            float axr[4], axi[4];
#pragma unroll
            for (int k = 0; k < 4; ++k) {
                axr[k] = tot[(i * 4 + k) * NCH + tid];
                axi[k] = tot[(16 + i * 4 + k) * NCH + tid];
            }
#pragma unroll
            for (int j = 0; j < 4; ++j) {
                float s_r = 0.f, s_i = 0.f;
#pragma unroll
                for (int k = 0; k < 4; ++k) {
                    s_r = fmaf(axr[k], Ppr[k * 4 + j], s_r);
                    s_r = fmaf(-axi[k], Ppi[k * 4 + j], s_r);
                    s_i = fmaf(axr[k], Ppi[k * 4 + j], s_i);
                    s_i = fmaf(axi[k], Ppr[k * 4 + j], s_i);
                }
                cxr[i * 4 + j] = s_r;
                cxi[i * 4 + j] = s_i;
            }
        }
#pragma unroll
        for (int e = 0; e < 16; ++e) {
            carr[e * (NCH + 1) + tid + 1]        = cxr[e];
            carr[(16 + e) * (NCH + 1) + tid + 1] = cxi[e];
        }
        // publish block-inclusive prefix (carr col 64) with 32 parallel lanes
        if (blockT != BPB - 1) {
            if (tid < 32) {
                const float v = carr[tid * (NCH + 1) + NCH];  // lgkm-waited by compiler
                __hip_atomic_store(
                    reinterpret_cast<unsigned int*>(prefix) + (size_t)bid * 32 + tid,
                    __float_as_uint(v), __ATOMIC_RELAXED, __HIP_MEMORY_SCOPE_AGENT);
            }
            if (tid == 0) {
                __hip_atomic_store(flag + bid, 1u, __ATOMIC_RELEASE,
                                   __HIP_MEMORY_SCOPE_AGENT);  // vmcnt(0)-drained release
            }
        }
    }
    __syncthreads();

    // ---------------- phase 3: out[t][b] = L @ carry(chunk) ------------------
    {
        float c_r[16], c_i[16];
#pragma unroll
        for (int e = 0; e < 16; ++e) {
            c_r[e] = carr[e * (NCH + 1) + c];        // broadcast per 8-lane group
            c_i[e] = carr[(16 + e) * (NCH + 1) + c];
        }
        float o_r[16], o_i[16];
        cmm(er, ei, c_r, c_i, o_r, o_i);

        // each half-matrix = one aligned 64-B sector per lane (full-line writes)
        const size_t oi = ((size_t)t * BB + b) * 16;
        float4* orp = reinterpret_cast<float4*>(out + oi);
        float4* oip = reinterpret_cast<float4*>(out + HALF + oi);
#pragma unroll
        for (int w = 0; w < 4; ++w) {
            orp[w] = make_float4(o_r[w * 4 + 0], o_r[w * 4 + 1], o_r[w * 4 + 2], o_r[w * 4 + 3]);
            oip[w] = make_float4(o_i[w * 4 + 0], o_i[w * 4 + 1], o_i[w * 4 + 2], o_i[w * 4 + 3]);
        }
    }
}

extern "C" void kernel_launch(void* const* d_in, const int* in_sizes, int n_in,
                              void* d_out, int out_size, void* d_ws, size_t ws_size,
                              hipStream_t stream) {
    const float* hr = (const float*)d_in[0];
    const float* hi = (const float*)d_in[1];
    const float* sr = (const float*)d_in[2];
    const float* si = (const float*)d_in[3];
    float* out    = (float*)d_out;
    float* prefix = (float*)d_ws;                                  // 512*32 floats = 64 KB
    unsigned int* flag = (unsigned int*)((float*)d_ws + (size_t)NBLK * 32);  // 512 uints

    k_init<<<1, NBLK, 0, stream>>>(flag);
    k_main<<<NBLK, TPB, 0, stream>>>(hr, hi, sr, si, out, prefix, flag);
}